// Round 1
// baseline (1200.998 us; speedup 1.0000x reference)
//
#include <hip/hip_runtime.h>
#include <math.h>

// Problem constants (B=4, H=256, W=256, K=3 Gauss-Hermite, 100 iters)
#define NPIX  262144   // 4*256*256
#define NEDGE 524288   // NPIX*2
#define ITERS 100

__device__ __forceinline__ float clampf(float x, float lo, float hi) {
    return fminf(fmaxf(x, lo), hi);
}

struct EdgeOut { float dmu_a, dmu_b, dsg_a, dsg_b, drou; };

// Pairwise quadrature terms for one edge a->b.
// a = edge owner (holds rou, ew); b = neighbor (down or right).
// Returns natural-gradient contributions for both endpoints + drou (owned by a).
__device__ __forceinline__ EdgeOut edge_terms(float mu_a, float sg_a, float rou, float ew,
                                              float mu_b, float sg_b) {
    const float SQRT2F = 1.41421356237309515f;
    const float NDCF   = 0.91893853320467274f;   // 0.5*log(2*pi)
    const float c      = 1.22474487139158905f;   // sqrt(1.5), GH-3 node
    const float xs[3] = {-c, 0.f, c};
    const float wq[3] = {1.f/6.f, 2.f/3.f, 1.f/6.f};

    float q   = 1.f - rou*rou;
    float rtq = sqrtf(q);
    float s   = 0.5f*sqrtf(1.f + rou);
    float r   = 0.5f*sqrtf(1.f - rou);
    float ap = s + r, am = s - r;
    float C  = 2.f*NDCF + logf(sg_a*sg_b) + 0.5f*logf(q);
    float k1 = sg_a*SQRT2F, k2 = sg_b*SQRT2F;

    float S1=0.f, S2=0.f, SA=0.f, SM=0.f, SR=0.f;
#pragma unroll
    for (int i = 0; i < 3; ++i) {
#pragma unroll
        for (int j = 0; j < 3; ++j) {
            float xi = xs[i], xj = xs[j];
            float we = wq[i]*wq[j];
            float z1 = ap*xi + am*xj;
            float z2 = am*xi + ap*xj;
            float fe = (ew*(k1*z1 + mu_a)*(k2*z2 + mu_b) + C)*we;
            S1 += fe*(z1 - rou*z2);
            S2 += fe*(z2 - rou*z1);
            float A = xi*xi + xj*xj - 1.f;   // XI2AXJ2
            float M = xi*xi - xj*xj;          // XI2MXJ2
            SA += fe*A;
            SM += fe*M;
            SR += fe*(2.f*xi*xj - rou*A);     // 2*XIJ - rou*XI2AXJ2
        }
    }
    float inv_q = 1.f/q;
    EdgeOut o;
    o.dmu_a = S1*inv_q/sg_a*SQRT2F;
    o.dmu_b = S2*inv_q/sg_b*SQRT2F;
    float smr = SM/rtq;
    o.dsg_a = (SA + smr)/sg_a;
    o.dsg_b = (SA - smr)/sg_b;
    o.drou  = SR*inv_q;
    return o;
}

// One Jacobi iteration (gather formulation: each pixel recomputes the
// neighbor-side terms of its incoming up/left edges from prev-state).
__global__ __launch_bounds__(256) void step_kernel(
    const float* __restrict__ muI, const float* __restrict__ sgI,
    const float* __restrict__ r0I, const float* __restrict__ r1I,
    float* __restrict__ muO, float* __restrict__ sgO,
    float* __restrict__ r0O, float* __restrict__ r1O,
    float* __restrict__ v0p, float* __restrict__ v1p,
    float* __restrict__ v2p, float* __restrict__ v3p,
    const float*  __restrict__ y,
    const float2* __restrict__ ew,
    const float2* __restrict__ uw)
{
    const float SQRT2F = 1.41421356237309515f;
    const float NDCF   = 0.91893853320467274f;
    const float c      = 1.22474487139158905f;

    int bh = blockIdx.x;            // b*256 + h
    int w  = threadIdx.x;
    int h  = bh & 255;
    int bbase = bh & ~255;          // b*256
    int idx    = (bh << 8) | w;
    int idx_dn = ((bbase | ((h+1)&255)) << 8) | w;
    int idx_up = ((bbase | ((h-1)&255)) << 8) | w;
    int idx_rt = (bh << 8) | ((w+1)&255);
    int idx_lf = (bh << 8) | ((w-1)&255);

    float mu = muI[idx],  sg = sgI[idx];
    float r0 = r0I[idx],  r1 = r1I[idx];
    float mu_dn = muI[idx_dn], sg_dn = sgI[idx_dn];
    float mu_rt = muI[idx_rt], sg_rt = sgI[idx_rt];
    float mu_up = muI[idx_up], sg_up = sgI[idx_up];
    float mu_lf = muI[idx_lf], sg_lf = sgI[idx_lf];
    float r0_up = r0I[idx_up];
    float r1_lf = r1I[idx_lf];
    float2 ew_own = ew[idx];
    float  ew0_up = ew[idx_up].x;
    float  ew1_lf = ew[idx_lf].y;
    float2 uwv = uw[idx];
    float  yv  = y[idx];
    float v0 = v0p[idx], v1 = v1p[idx], v2 = v2p[idx], v3 = v3p[idx];

    // ---- unary quadrature (3 points; XN={-c,0,c}, WN={1/6,2/3,1/6}, X22={2,-1,2})
    float log_sg = logf(sg);
    float base3  = 3.f*(NDCF + log_sg);
    float k  = sg*SQRT2F;
    float x0 = mu - c*k, x1 = mu, x2 = mu + c*k;
    float f0 = (x0*(uwv.x*x0 + uwv.y*yv) - base3)*(1.f/6.f);
    float f1 = (x1*(uwv.x*x1 + uwv.y*yv) - base3)*(2.f/3.f);
    float f2 = (x2*(uwv.x*x2 + uwv.y*yv) - base3)*(1.f/6.f);
    float inv_sg = 1.f/sg;
    float dmu = (f2 - f0)*c*inv_sg*SQRT2F;       // sum(fn*XN)/sg*sqrt2
    float dsg = (2.f*(f0 + f2) - f1)*inv_sg;     // sum(fn*X22)/sg

    // ---- outgoing edges (own rou/ew)
    EdgeOut e0 = edge_terms(mu, sg, r0, ew_own.x, mu_dn, sg_dn);
    dmu += e0.dmu_a; dsg += e0.dsg_a; float dr0 = e0.drou;
    EdgeOut e1 = edge_terms(mu, sg, r1, ew_own.y, mu_rt, sg_rt);
    dmu += e1.dmu_a; dsg += e1.dsg_a; float dr1 = e1.drou;

    // ---- incoming edges (gather of the rolled dmu2/dsigma2 terms)
    EdgeOut eu = edge_terms(mu_up, sg_up, r0_up, ew0_up, mu, sg);
    dmu += eu.dmu_b; dsg += eu.dsg_b;
    EdgeOut el = edge_terms(mu_lf, sg_lf, r1_lf, ew1_lf, mu, sg);
    dmu += el.dmu_b; dsg += el.dsg_b;

    // ---- momentum + clipped apply
    v0 = 0.7f*v0 + 0.01f*dmu;
    v1 = 0.7f*v1 + 0.01f*dsg;
    v2 = 0.7f*v2 + 0.01f*dr0;
    v3 = 0.7f*v3 + 0.01f*dr1;
    v0p[idx] = v0; v1p[idx] = v1; v2p[idx] = v2; v3p[idx] = v3;
    muO[idx] = clampf(mu + v0, 0.f, 63.f);
    sgO[idx] = clampf(sg + v1, 0.001f, 50.f);
    r0O[idx] = clampf(r0 + v2, -0.99f, 0.99f);
    r1O[idx] = clampf(r1 + v3, -0.99f, 0.99f);
}

// ---- global max(edge_weight) via order-preserving uint encoding ----
__global__ void init_max_kernel(unsigned int* gmax) {
    if (threadIdx.x == 0 && blockIdx.x == 0) *gmax = 0u;  // encodes "-max float"
}

__global__ void reduce_max_kernel(const float* __restrict__ ew, unsigned int* gmax) {
    int i = blockIdx.x*blockDim.x + threadIdx.x;
    float m = -INFINITY;
    for (; i < NEDGE; i += gridDim.x*blockDim.x) m = fmaxf(m, ew[i]);
#pragma unroll
    for (int off = 32; off > 0; off >>= 1)
        m = fmaxf(m, __shfl_down(m, off, 64));
    if ((threadIdx.x & 63) == 0) {
        unsigned u = __float_as_uint(m);
        unsigned key = (u & 0x80000000u) ? ~u : (u | 0x80000000u);
        atomicMax(gmax, key);
    }
}

__global__ __launch_bounds__(256) void init_state_kernel(
    const float* __restrict__ y, const float2* __restrict__ ew,
    const unsigned int* __restrict__ gmax_enc,
    float* muA, float* sgA, float* r0A, float* r1A,
    float* v0p, float* v1p, float* v2p, float* v3p)
{
    int idx = blockIdx.x*256 + threadIdx.x;
    unsigned key = *gmax_enc;
    unsigned u = (key & 0x80000000u) ? (key ^ 0x80000000u) : ~key;
    float gmax = __uint_as_float(u);
    float denom = gmax*1.01f + 1.f;
    float2 e = ew[idx];
    muA[idx] = y[idx];
    sgA[idx] = 1.f;
    r0A[idx] = e.x / denom;
    r1A[idx] = e.y / denom;
    v0p[idx] = 0.f; v1p[idx] = 0.f; v2p[idx] = 0.f; v3p[idx] = 0.f;
}

extern "C" void kernel_launch(void* const* d_in, const int* in_sizes, int n_in,
                              void* d_out, int out_size, void* d_ws, size_t ws_size,
                              hipStream_t stream) {
    const float* y  = (const float*)d_in[0];
    const float* ew = (const float*)d_in[1];
    const float* uw = (const float*)d_in[2];
    float* ws = (float*)d_ws;
    const int N = NPIX;

    // workspace layout: 12 N-float planes + 1 uint  (~12.6 MB)
    float* muA = ws + 0*N;  float* muB = ws + 1*N;
    float* sgA = ws + 2*N;  float* sgB = ws + 3*N;
    float* r0A = ws + 4*N;  float* r0B = ws + 5*N;
    float* r1A = ws + 6*N;  float* r1B = ws + 7*N;
    float* v0p = ws + 8*N;  float* v1p = ws + 9*N;
    float* v2p = ws + 10*N; float* v3p = ws + 11*N;
    unsigned int* gmax = (unsigned int*)(ws + 12*N);

    hipLaunchKernelGGL(init_max_kernel, dim3(1), dim3(64), 0, stream, gmax);
    hipLaunchKernelGGL(reduce_max_kernel, dim3(512), dim3(256), 0, stream, ew, gmax);
    hipLaunchKernelGGL(init_state_kernel, dim3(N/256), dim3(256), 0, stream,
                       y, (const float2*)ew, gmax,
                       muA, sgA, r0A, r1A, v0p, v1p, v2p, v3p);

    float *muI=muA, *sgI=sgA, *r0I=r0A, *r1I=r1A;
    float *muO=muB, *sgO=sgB, *r0O=r0B, *r1O=r1B;
    for (int it = 0; it < ITERS; ++it) {
        float* mo = (it == ITERS-1) ? (float*)d_out : muO;
        hipLaunchKernelGGL(step_kernel, dim3(1024), dim3(256), 0, stream,
                           muI, sgI, r0I, r1I,
                           mo, sgO, r0O, r1O,
                           v0p, v1p, v2p, v3p,
                           y, (const float2*)ew, (const float2*)uw);
        float* t;
        t=muI; muI=muO; muO=t;
        t=sgI; sgI=sgO; sgO=t;
        t=r0I; r0I=r0O; r0O=t;
        t=r1I; r1I=r1O; r1O=t;
    }
}

// Round 2
// 968.392 us; speedup vs baseline: 1.2402x; 1.2402x over previous
//
#include <hip/hip_runtime.h>
#include <math.h>

// Problem constants (B=4, H=256, W=256, K=3 Gauss-Hermite, 100 iters)
#define NPIX  262144   // 4*256*256
#define NEDGE 524288   // NPIX*2
#define ITERS 100

__device__ __forceinline__ float clampf(float x, float lo, float hi) {
    return fminf(fmaxf(x, lo), hi);
}
// Fast single-instruction transcendentals (v_rcp/v_rsq/v_sqrt/v_log), ~1 ulp.
__device__ __forceinline__ float frcp(float x)  { return __builtin_amdgcn_rcpf(x); }
__device__ __forceinline__ float frsq(float x)  { return __builtin_amdgcn_rsqf(x); }
__device__ __forceinline__ float fsqrt(float x) { return __builtin_amdgcn_sqrtf(x); }
__device__ __forceinline__ float fln(float x)   { return __builtin_amdgcn_logf(x)*0.69314718055994531f; }

struct EdgeOut { float dmu_a, dmu_b, dsg_a, dsg_b, drou; };

// Pairwise quadrature terms for one edge a->b (a owns rou, ew).
// inv_sg / log_sg for both endpoints are precomputed per pixel and passed in.
__device__ __forceinline__ EdgeOut edge_terms(
    float mu_a, float sg_a, float inv_sga, float log_sga,
    float rou, float ew,
    float mu_b, float sg_b, float inv_sgb, float log_sgb)
{
    const float SQRT2F = 1.41421356237309515f;
    const float NDCF   = 0.91893853320467274f;   // 0.5*log(2*pi)
    const float c      = 1.22474487139158905f;   // sqrt(1.5), GH-3 node
    const float xs[3] = {-c, 0.f, c};
    const float wq[3] = {1.f/6.f, 2.f/3.f, 1.f/6.f};

    float q       = 1.f - rou*rou;
    float inv_rtq = frsq(q);                      // 1/sqrt(q)
    float s  = 0.5f*fsqrt(1.f + rou);
    float r  = 0.5f*fsqrt(1.f - rou);
    float ap = s + r, am = s - r;
    float C  = 2.f*NDCF + log_sga + log_sgb + 0.5f*fln(q);
    float k1 = sg_a*SQRT2F, k2 = sg_b*SQRT2F;

    float S1=0.f, S2=0.f, SA=0.f, SM=0.f, SR=0.f;
#pragma unroll
    for (int i = 0; i < 3; ++i) {
#pragma unroll
        for (int j = 0; j < 3; ++j) {
            float xi = xs[i], xj = xs[j];
            float we = wq[i]*wq[j];
            float z1 = ap*xi + am*xj;
            float z2 = am*xi + ap*xj;
            float fe = (ew*(k1*z1 + mu_a)*(k2*z2 + mu_b) + C)*we;
            S1 += fe*(z1 - rou*z2);
            S2 += fe*(z2 - rou*z1);
            float A = xi*xi + xj*xj - 1.f;   // XI2AXJ2 (compile-time const)
            float M = xi*xi - xj*xj;          // XI2MXJ2 (compile-time const)
            SA += fe*A;
            SM += fe*M;
            SR += fe*(2.f*xi*xj - rou*A);     // 2*XIJ - rou*XI2AXJ2
        }
    }
    float inv_q = frcp(q);
    EdgeOut o;
    o.dmu_a = S1*inv_q*inv_sga*SQRT2F;
    o.dmu_b = S2*inv_q*inv_sgb*SQRT2F;
    float smr = SM*inv_rtq;
    o.dsg_a = (SA + smr)*inv_sga;
    o.dsg_b = (SA - smr)*inv_sgb;
    o.drou  = SR*inv_q;
    return o;
}

// State packed as float4 {mu, sigma, rou0(down), rou1(right)}; v as float4.
__global__ __launch_bounds__(256) void step_kernel(
    const float4* __restrict__ stI, float4* __restrict__ stO,
    float4* __restrict__ vP,
    const float*  __restrict__ y,
    const float2* __restrict__ ew,
    const float2* __restrict__ uw,
    float* __restrict__ mu_out)   // non-null on last iteration
{
    const float SQRT2F = 1.41421356237309515f;
    const float NDCF   = 0.91893853320467274f;
    const float c      = 1.22474487139158905f;

    int bh = blockIdx.x;            // b*256 + h
    int w  = threadIdx.x;
    int h  = bh & 255;
    int bbase = bh & ~255;          // b*256
    int idx    = (bh << 8) | w;
    int idx_dn = ((bbase | ((h+1)&255)) << 8) | w;
    int idx_up = ((bbase | ((h-1)&255)) << 8) | w;
    int idx_rt = (bh << 8) | ((w+1)&255);
    int idx_lf = (bh << 8) | ((w-1)&255);

    float4 st    = stI[idx];
    float4 st_dn = stI[idx_dn];
    float4 st_up = stI[idx_up];
    float4 st_rt = stI[idx_rt];
    float4 st_lf = stI[idx_lf];
    float2 ew_own = ew[idx];
    float  ew0_up = ew[idx_up].x;
    float  ew1_lf = ew[idx_lf].y;
    float2 uwv = uw[idx];
    float  yv  = y[idx];
    float4 v   = vP[idx];

    float mu = st.x, sg = st.y, r0 = st.z, r1 = st.w;

    // per-pixel hoisted transcendentals (self + 4 neighbors)
    float inv_sg    = frcp(sg),      log_sg    = fln(sg);
    float inv_sg_dn = frcp(st_dn.y), log_sg_dn = fln(st_dn.y);
    float inv_sg_up = frcp(st_up.y), log_sg_up = fln(st_up.y);
    float inv_sg_rt = frcp(st_rt.y), log_sg_rt = fln(st_rt.y);
    float inv_sg_lf = frcp(st_lf.y), log_sg_lf = fln(st_lf.y);

    // ---- unary quadrature (XN={-c,0,c}, WN={1/6,2/3,1/6}, X22={2,-1,2})
    float base3 = 3.f*(NDCF + log_sg);
    float k  = sg*SQRT2F;
    float x0 = mu - c*k, x1 = mu, x2 = mu + c*k;
    float f0 = (x0*(uwv.x*x0 + uwv.y*yv) - base3)*(1.f/6.f);
    float f1 = (x1*(uwv.x*x1 + uwv.y*yv) - base3)*(2.f/3.f);
    float f2 = (x2*(uwv.x*x2 + uwv.y*yv) - base3)*(1.f/6.f);
    float dmu = (f2 - f0)*c*inv_sg*SQRT2F;
    float dsg = (2.f*(f0 + f2) - f1)*inv_sg;

    // ---- outgoing edges (own rou/ew)
    EdgeOut e0 = edge_terms(mu, sg, inv_sg, log_sg, r0, ew_own.x,
                            st_dn.x, st_dn.y, inv_sg_dn, log_sg_dn);
    dmu += e0.dmu_a; dsg += e0.dsg_a; float dr0 = e0.drou;
    EdgeOut e1 = edge_terms(mu, sg, inv_sg, log_sg, r1, ew_own.y,
                            st_rt.x, st_rt.y, inv_sg_rt, log_sg_rt);
    dmu += e1.dmu_a; dsg += e1.dsg_a; float dr1 = e1.drou;

    // ---- incoming edges (gather of the rolled dmu2/dsigma2 terms)
    EdgeOut eu = edge_terms(st_up.x, st_up.y, inv_sg_up, log_sg_up, st_up.z, ew0_up,
                            mu, sg, inv_sg, log_sg);
    dmu += eu.dmu_b; dsg += eu.dsg_b;
    EdgeOut el = edge_terms(st_lf.x, st_lf.y, inv_sg_lf, log_sg_lf, st_lf.w, ew1_lf,
                            mu, sg, inv_sg, log_sg);
    dmu += el.dmu_b; dsg += el.dsg_b;

    // ---- momentum + clipped apply
    v.x = 0.7f*v.x + 0.01f*dmu;
    v.y = 0.7f*v.y + 0.01f*dsg;
    v.z = 0.7f*v.z + 0.01f*dr0;
    v.w = 0.7f*v.w + 0.01f*dr1;
    vP[idx] = v;
    float4 o;
    o.x = clampf(mu + v.x, 0.f, 63.f);
    o.y = clampf(sg + v.y, 0.001f, 50.f);
    o.z = clampf(r0 + v.z, -0.99f, 0.99f);
    o.w = clampf(r1 + v.w, -0.99f, 0.99f);
    stO[idx] = o;
    if (mu_out) mu_out[idx] = o.x;
}

// ---- global max(edge_weight) via order-preserving uint encoding ----
__global__ void init_max_kernel(unsigned int* gmax) {
    if (threadIdx.x == 0 && blockIdx.x == 0) *gmax = 0u;
}

__global__ void reduce_max_kernel(const float* __restrict__ ew, unsigned int* gmax) {
    int i = blockIdx.x*blockDim.x + threadIdx.x;
    float m = -INFINITY;
    for (; i < NEDGE; i += gridDim.x*blockDim.x) m = fmaxf(m, ew[i]);
#pragma unroll
    for (int off = 32; off > 0; off >>= 1)
        m = fmaxf(m, __shfl_down(m, off, 64));
    if ((threadIdx.x & 63) == 0) {
        unsigned u = __float_as_uint(m);
        unsigned key = (u & 0x80000000u) ? ~u : (u | 0x80000000u);
        atomicMax(gmax, key);
    }
}

__global__ __launch_bounds__(256) void init_state_kernel(
    const float* __restrict__ y, const float2* __restrict__ ew,
    const unsigned int* __restrict__ gmax_enc,
    float4* stA, float4* vP)
{
    int idx = blockIdx.x*256 + threadIdx.x;
    unsigned key = *gmax_enc;
    unsigned u = (key & 0x80000000u) ? (key ^ 0x80000000u) : ~key;
    float gmax = __uint_as_float(u);
    float inv_denom = 1.f / (gmax*1.01f + 1.f);   // one-time, IEEE div fine
    float2 e = ew[idx];
    float4 st;
    st.x = y[idx];
    st.y = 1.f;
    st.z = e.x * inv_denom;
    st.w = e.y * inv_denom;
    stA[idx] = st;
    vP[idx] = make_float4(0.f, 0.f, 0.f, 0.f);
}

extern "C" void kernel_launch(void* const* d_in, const int* in_sizes, int n_in,
                              void* d_out, int out_size, void* d_ws, size_t ws_size,
                              hipStream_t stream) {
    const float* y  = (const float*)d_in[0];
    const float* ew = (const float*)d_in[1];
    const float* uw = (const float*)d_in[2];
    const int N = NPIX;

    // workspace: two float4 state planes + one float4 v plane + 1 uint (~12.6 MB)
    float4* stA = (float4*)d_ws;
    float4* stB = stA + N;
    float4* vP  = stB + N;
    unsigned int* gmax = (unsigned int*)(vP + N);

    hipLaunchKernelGGL(init_max_kernel, dim3(1), dim3(64), 0, stream, gmax);
    hipLaunchKernelGGL(reduce_max_kernel, dim3(512), dim3(256), 0, stream, ew, gmax);
    hipLaunchKernelGGL(init_state_kernel, dim3(N/256), dim3(256), 0, stream,
                       y, (const float2*)ew, gmax, stA, vP);

    float4 *stI = stA, *stO = stB;
    for (int it = 0; it < ITERS; ++it) {
        float* mo = (it == ITERS-1) ? (float*)d_out : nullptr;
        hipLaunchKernelGGL(step_kernel, dim3(1024), dim3(256), 0, stream,
                           stI, stO, vP,
                           y, (const float2*)ew, (const float2*)uw, mo);
        float4* t = stI; stI = stO; stO = t;
    }
}

// Round 4
// 701.315 us; speedup vs baseline: 1.7125x; 1.3808x over previous
//
#include <hip/hip_runtime.h>
#include <math.h>

// Problem constants (B=4, H=256, W=256, 100 iters)
// The 3-pt Gauss-Hermite quadrature in the reference is EXACT (all integrands
// are per-variable degree <= 4 < 5), so every quadrature sum equals its
// closed-form Gaussian moment. The log/NDC terms multiply exactly-zero-mean
// factors and vanish. Surviving update per pixel:
//   dmu  = 2*uw1*mu + uw2*y + sum_edges ew*mu_nb
//   dsg  = 2*uw1*sg + sum_edges ew*rou_edge*sg_nb
//   drou = ew*sg_self*sg_nb          (per owned edge)
#define NPIX  262144   // 4*256*256
#define NEDGE 524288
#define ITERS 100

__device__ __forceinline__ float clampf(float x, float lo, float hi) {
    return fminf(fmaxf(x, lo), hi);
}

// State packed as float4 {mu, sigma, rou0(down-edge), rou1(right-edge)}.
// c1 = {2*uw1, uw2*y, ew0, ew1}; c2 = {ew0 of up-neighbor, ew1 of left-neighbor}.
__global__ __launch_bounds__(256) void step_kernel(
    const float4* __restrict__ stI, float4* __restrict__ stO,
    float4* __restrict__ vP,
    const float4* __restrict__ c1,
    const float2* __restrict__ c2,
    float* __restrict__ mu_out)   // non-null on last iteration
{
    int bh = blockIdx.x;            // b*256 + h
    int w  = threadIdx.x;
    int h  = bh & 255;
    int bbase = bh & ~255;          // b*256
    int idx    = (bh << 8) | w;
    int idx_dn = ((bbase | ((h+1)&255)) << 8) | w;
    int idx_up = ((bbase | ((h-1)&255)) << 8) | w;
    int idx_rt = (bh << 8) | ((w+1)&255);
    int idx_lf = (bh << 8) | ((w-1)&255);

    float4 st    = stI[idx];
    float4 st_dn = stI[idx_dn];
    float4 st_up = stI[idx_up];
    float4 st_rt = stI[idx_rt];
    float4 st_lf = stI[idx_lf];
    float4 k  = c1[idx];
    float2 k2 = c2[idx];
    float4 v  = vP[idx];

    // closed-form natural gradients
    float dmu = k.x*st.x + k.y
              + k.z*st_dn.x + k.w*st_rt.x          // outgoing: ew*mu_nb
              + k2.x*st_up.x + k2.y*st_lf.x;       // incoming: ew*mu_nb
    float dsg = k.x*st.y
              + k.z*st.z*st_dn.y + k.w*st.w*st_rt.y        // ew*rou*sg_nb
              + k2.x*st_up.z*st_up.y + k2.y*st_lf.w*st_lf.y;
    float dr0 = k.z*st.y*st_dn.y;                  // ew0*sg*sg_dn
    float dr1 = k.w*st.y*st_rt.y;                  // ew1*sg*sg_rt

    // momentum + clipped apply
    v.x = 0.7f*v.x + 0.01f*dmu;
    v.y = 0.7f*v.y + 0.01f*dsg;
    v.z = 0.7f*v.z + 0.01f*dr0;
    v.w = 0.7f*v.w + 0.01f*dr1;
    vP[idx] = v;
    float4 o;
    o.x = clampf(st.x + v.x, 0.f, 63.f);
    o.y = clampf(st.y + v.y, 0.001f, 50.f);
    o.z = clampf(st.z + v.z, -0.99f, 0.99f);
    o.w = clampf(st.w + v.w, -0.99f, 0.99f);
    stO[idx] = o;
    if (mu_out) mu_out[idx] = o.x;
}

// ---- global max(edge_weight) via order-preserving uint encoding ----
__global__ void init_max_kernel(unsigned int* gmax) {
    if (threadIdx.x == 0 && blockIdx.x == 0) *gmax = 0u;  // encodes "-max float"
}

__global__ void reduce_max_kernel(const float* __restrict__ ew, unsigned int* gmax) {
    int i = blockIdx.x*blockDim.x + threadIdx.x;
    float m = -INFINITY;
    for (; i < NEDGE; i += gridDim.x*blockDim.x) m = fmaxf(m, ew[i]);
#pragma unroll
    for (int off = 32; off > 0; off >>= 1)
        m = fmaxf(m, __shfl_down(m, off, 64));
    if ((threadIdx.x & 63) == 0) {
        unsigned u = __float_as_uint(m);
        unsigned key = (u & 0x80000000u) ? ~u : (u | 0x80000000u);
        atomicMax(gmax, key);
    }
}

// init state + pre-pack per-pixel invariant coefficients
__global__ __launch_bounds__(256) void init_state_kernel(
    const float*  __restrict__ y,
    const float2* __restrict__ ew,
    const float2* __restrict__ uw,
    const unsigned int* __restrict__ gmax_enc,
    float4* stA, float4* vP, float4* c1, float2* c2)
{
    int bh = blockIdx.x;
    int w  = threadIdx.x;
    int h  = bh & 255;
    int bbase = bh & ~255;
    int idx    = (bh << 8) | w;
    int idx_up = ((bbase | ((h-1)&255)) << 8) | w;
    int idx_lf = (bh << 8) | ((w-1)&255);

    unsigned key = *gmax_enc;
    unsigned u = (key & 0x80000000u) ? (key ^ 0x80000000u) : ~key;
    float gmax = __uint_as_float(u);
    float inv_denom = 1.f / (gmax*1.01f + 1.f);   // one-time, IEEE div fine

    float2 e  = ew[idx];
    float2 uwv = uw[idx];
    float  yv = y[idx];
    float4 st;
    st.x = yv;
    st.y = 1.f;
    st.z = e.x * inv_denom;
    st.w = e.y * inv_denom;
    stA[idx] = st;
    vP[idx]  = make_float4(0.f, 0.f, 0.f, 0.f);
    c1[idx]  = make_float4(2.f*uwv.x, uwv.y*yv, e.x, e.y);
    c2[idx]  = make_float2(ew[idx_up].x, ew[idx_lf].y);
}

extern "C" void kernel_launch(void* const* d_in, const int* in_sizes, int n_in,
                              void* d_out, int out_size, void* d_ws, size_t ws_size,
                              hipStream_t stream) {
    const float* y  = (const float*)d_in[0];
    const float* ew = (const float*)d_in[1];
    const float* uw = (const float*)d_in[2];
    const int N = NPIX;

    // workspace: stA, stB, vP, c1 (float4 planes) + c2 (float2) + 1 uint (~19 MB)
    float4* stA = (float4*)d_ws;
    float4* stB = stA + N;
    float4* vP  = stB + N;
    float4* c1  = vP + N;
    float2* c2  = (float2*)(c1 + N);
    unsigned int* gmax = (unsigned int*)(c2 + N);

    hipLaunchKernelGGL(init_max_kernel, dim3(1), dim3(64), 0, stream, gmax);
    hipLaunchKernelGGL(reduce_max_kernel, dim3(512), dim3(256), 0, stream, ew, gmax);
    hipLaunchKernelGGL(init_state_kernel, dim3(N/256), dim3(256), 0, stream,
                       y, (const float2*)ew, (const float2*)uw, gmax,
                       stA, vP, c1, c2);

    float4 *stI = stA, *stO = stB;
    for (int it = 0; it < ITERS; ++it) {
        float* mo = (it == ITERS-1) ? (float*)d_out : nullptr;
        hipLaunchKernelGGL(step_kernel, dim3(1024), dim3(256), 0, stream,
                           stI, stO, vP, c1, c2, mo);
        float4* t = stI; stI = stO; stO = t;
    }
}

// Round 5
// 269.312 us; speedup vs baseline: 4.4595x; 2.6041x over previous
//
#include <hip/hip_runtime.h>
#include <math.h>

// B=4, H=256, W=256, 100 iters. Closed-form update (3-pt GH quadrature is
// exact for these degree<=4 integrands; log/NDC terms cancel):
//   dmu  = 2*uw1*mu + uw2*y + sum_edges ew*mu_nb
//   dsg  = 2*uw1*sg + sum_edges ew*rou_edge*sg_nb
//   drou = ew*sg_self*sg_nb        (per owned edge)
// Temporal blocking: T=10 iters per launch, 52x52 halo tile -> 32x32 interior.
#define NPIX  262144
#define NEDGE 524288
#define ITERS 100
#define T     10
#define TILE  52           // 32 + 2*T
#define NRG   18           // rowgroups of 3 rows (covers 52 rows, last partial)
#define ACTIVE (TILE*NRG)  // 936 active threads of 1024

__device__ __forceinline__ float clampf(float x, float lo, float hi) {
    return fminf(fmaxf(x, lo), hi);
}

// State float4 {mu, sigma, rou0(down-edge), rou1(right-edge)}.
// Each thread owns a vertical 3-strip (rows 3*rg..3*rg+2, one column):
// up/down neighbors are in-thread registers except at strip ends.
__global__ __launch_bounds__(1024) void tile_kernel(
    const float4* __restrict__ stI, const float4* __restrict__ vI,
    float4* __restrict__ stO, float4* __restrict__ vO,
    const float*  __restrict__ y,
    const float2* __restrict__ ew,
    const float2* __restrict__ uw,
    float* __restrict__ mu_out)   // non-null on last launch
{
    __shared__ float4 tile[TILE*TILE];

    int tid = threadIdx.x;
    int rg  = tid / TILE;           // const-div -> magic mul
    int col = tid - rg*TILE;
    bool act = (tid < ACTIVE);
    int bz = blockIdx.z;
    int h0 = blockIdx.y * 32;
    int w0 = blockIdx.x * 32;
    int w  = (w0 + col - T) & 255;

    float4 st[3], v[3], k1[3];
    float2 k2[3];
    int gidx[3];

    // ---- load tile: st -> LDS + regs; v, coefficients -> regs ----
    if (act) {
#pragma unroll
        for (int k = 0; k < 3; ++k) {
            int r = 3*rg + k;
            if (r < TILE) {
                int h = (h0 + r - T) & 255;
                int g = (bz << 16) | (h << 8) | w;
                gidx[k] = g;
                float4 s = stI[g];
                st[k] = s;
                tile[r*TILE + col] = s;
                v[k] = vI[g];
                float2 e   = ew[g];
                float2 uwv = uw[g];
                float  yv  = y[g];
                k1[k] = make_float4(2.f*uwv.x, uwv.y*yv, e.x, e.y);
                int gup = (bz << 16) | (((h-1) & 255) << 8) | w;
                int glf = (bz << 16) | (h << 8) | ((w-1) & 255);
                k2[k] = make_float2(ew[gup].x, ew[glf].y);
            }
        }
    }
    __syncthreads();

    // ---- T fused Jacobi iterations with shrinking validity ----
    for (int s = 0; s < T; ++s) {
        float4 ns[3];
        bool u[3] = {false, false, false};
        if (act) {
#pragma unroll
            for (int k = 0; k < 3; ++k) {
                int r = 3*rg + k;
                bool upd = (r >= s+1) && (r <= 50-s) && (col >= s+1) && (col <= 50-s);
                u[k] = upd;
                if (upd) {
                    float4 lf = tile[r*TILE + col - 1];
                    float4 rt = tile[r*TILE + col + 1];
                    float4 up = (k == 0) ? tile[(r-1)*TILE + col] : st[k-1];
                    float4 dn = (k == 2) ? tile[(r+1)*TILE + col] : st[k+1];
                    float4 S = st[k];
                    float4 K = k1[k];
                    float2 K2 = k2[k];
                    float dmu = K.x*S.x + K.y + K.z*dn.x + K.w*rt.x
                              + K2.x*up.x + K2.y*lf.x;
                    float dsg = K.x*S.y + K.z*S.z*dn.y + K.w*S.w*rt.y
                              + K2.x*up.z*up.y + K2.y*lf.w*lf.y;
                    float dr0 = K.z*S.y*dn.y;
                    float dr1 = K.w*S.y*rt.y;
                    float4 V = v[k];
                    V.x = 0.7f*V.x + 0.01f*dmu;
                    V.y = 0.7f*V.y + 0.01f*dsg;
                    V.z = 0.7f*V.z + 0.01f*dr0;
                    V.w = 0.7f*V.w + 0.01f*dr1;
                    v[k] = V;
                    float4 o;
                    o.x = clampf(S.x + V.x, 0.f, 63.f);
                    o.y = clampf(S.y + V.y, 0.001f, 50.f);
                    o.z = clampf(S.z + V.z, -0.99f, 0.99f);
                    o.w = clampf(S.w + V.w, -0.99f, 0.99f);
                    ns[k] = o;
                }
            }
        }
        __syncthreads();   // all level-s reads done
        if (act) {
#pragma unroll
            for (int k = 0; k < 3; ++k) {
                if (u[k]) {
                    st[k] = ns[k];
                    tile[(3*rg + k)*TILE + col] = ns[k];
                }
            }
        }
        __syncthreads();   // level-(s+1) visible
    }

    // ---- store interior (rows/cols [T, T+32)) ----
    if (act && col >= T && col < T+32) {
#pragma unroll
        for (int k = 0; k < 3; ++k) {
            int r = 3*rg + k;
            if (r >= T && r < T+32) {
                int g = gidx[k];
                stO[g] = st[k];
                vO[g]  = v[k];
                if (mu_out) mu_out[g] = st[k].x;
            }
        }
    }
}

// ---- global max(edge_weight) via order-preserving uint encoding ----
__global__ void init_max_kernel(unsigned int* gmax) {
    if (threadIdx.x == 0 && blockIdx.x == 0) *gmax = 0u;
}

__global__ void reduce_max_kernel(const float* __restrict__ ew, unsigned int* gmax) {
    int i = blockIdx.x*blockDim.x + threadIdx.x;
    float m = -INFINITY;
    for (; i < NEDGE; i += gridDim.x*blockDim.x) m = fmaxf(m, ew[i]);
#pragma unroll
    for (int off = 32; off > 0; off >>= 1)
        m = fmaxf(m, __shfl_down(m, off, 64));
    if ((threadIdx.x & 63) == 0) {
        unsigned u = __float_as_uint(m);
        unsigned key = (u & 0x80000000u) ? ~u : (u | 0x80000000u);
        atomicMax(gmax, key);
    }
}

__global__ __launch_bounds__(256) void init_state_kernel(
    const float* __restrict__ y, const float2* __restrict__ ew,
    const unsigned int* __restrict__ gmax_enc,
    float4* stA, float4* vA)
{
    int idx = blockIdx.x*256 + threadIdx.x;
    unsigned key = *gmax_enc;
    unsigned u = (key & 0x80000000u) ? (key ^ 0x80000000u) : ~key;
    float gmax = __uint_as_float(u);
    float inv_denom = 1.f / (gmax*1.01f + 1.f);   // one-time, IEEE div fine
    float2 e = ew[idx];
    float4 st;
    st.x = y[idx];
    st.y = 1.f;
    st.z = e.x * inv_denom;
    st.w = e.y * inv_denom;
    stA[idx] = st;
    vA[idx] = make_float4(0.f, 0.f, 0.f, 0.f);
}

extern "C" void kernel_launch(void* const* d_in, const int* in_sizes, int n_in,
                              void* d_out, int out_size, void* d_ws, size_t ws_size,
                              hipStream_t stream) {
    const float* y  = (const float*)d_in[0];
    const float* ew = (const float*)d_in[1];
    const float* uw = (const float*)d_in[2];
    const int N = NPIX;

    // workspace: stA, stB, vA, vB (float4 planes, 16 MB) + 1 uint
    float4* stA = (float4*)d_ws;
    float4* stB = stA + N;
    float4* vA  = stB + N;
    float4* vB  = vA + N;
    unsigned int* gmax = (unsigned int*)(vB + N);

    hipLaunchKernelGGL(init_max_kernel, dim3(1), dim3(64), 0, stream, gmax);
    hipLaunchKernelGGL(reduce_max_kernel, dim3(512), dim3(256), 0, stream, ew, gmax);
    hipLaunchKernelGGL(init_state_kernel, dim3(N/256), dim3(256), 0, stream,
                       y, (const float2*)ew, gmax, stA, vA);

    float4 *stI = stA, *stO = stB, *vI = vA, *vO = vB;
    const int NLAUNCH = ITERS / T;   // 10
    for (int l = 0; l < NLAUNCH; ++l) {
        float* mo = (l == NLAUNCH-1) ? (float*)d_out : nullptr;
        hipLaunchKernelGGL(tile_kernel, dim3(8, 8, 4), dim3(1024), 0, stream,
                           stI, vI, stO, vO,
                           y, (const float2*)ew, (const float2*)uw, mo);
        float4* t;
        t = stI; stI = stO; stO = t;
        t = vI;  vI  = vO;  vO  = t;
    }
}

// Round 6
// 257.999 us; speedup vs baseline: 4.6550x; 1.0438x over previous
//
#include <hip/hip_runtime.h>
#include <math.h>

// B=4, H=256, W=256, 100 iters. Closed-form update (3-pt GH quadrature is
// exact for these degree<=4 integrands; log/NDC terms cancel):
//   dmu  = 2*uw1*mu + uw2*y + sum_edges ew*mu_nb
//   dsg  = 2*uw1*sg + sum_edges ew*rou_edge*sg_nb
//   drou = ew*sg_self*sg_nb        (per owned edge)
// Temporal blocking: T=10 iters/launch, 52x52 halo tile -> 32x32 interior.
// Round 6: double-buffered LDS (1 sync/iter), unconditional updates
// (shrinking-validity induction makes predicates unnecessary; everything is
// clamp-bounded so no NaN can propagate), L=4 row strips (13x52=676 threads,
// exact cover), precomputed c1/c2 coefficient planes, last launch stores mu only.
#define NPIX  262144
#define NEDGE 524288
#define ITERS 100
#define T     10
#define TILE  52            // 32 + 2*T
#define NRG   13            // rowgroups of 4 rows: 13*4 = 52 exact
#define ACTIVE (TILE*NRG)   // 676 active threads of 1024

__device__ __forceinline__ float clampf(float x, float lo, float hi) {
    return fminf(fmaxf(x, lo), hi);
}

// State float4 {mu, sigma, rou0(down-edge), rou1(right-edge)}.
// c1 = {2*uw1, uw2*y, ew0, ew1}; c2 = {ew0 of up-nb, ew1 of left-nb}.
__global__ __launch_bounds__(1024, 4) void tile_kernel(
    const float4* __restrict__ stI, const float4* __restrict__ vI,
    float4* __restrict__ stO, float4* __restrict__ vO,
    const float4* __restrict__ c1,
    const float2* __restrict__ c2,
    float* __restrict__ mu_out)   // non-null on last launch (then st/v not stored)
{
    __shared__ float4 buf[2][TILE*TILE];

    int tid = threadIdx.x;
    int rg  = tid / TILE;           // magic-mul div
    int col = tid - rg*TILE;
    bool act = (tid < ACTIVE);
    int bz = blockIdx.z;
    int h0 = blockIdx.y * 32;
    int w0 = blockIdx.x * 32;
    int w  = (w0 + col - T) & 255;

    float4 st[4], v[4], k1[4];
    float2 k2[4];
    int gidx[4];

    // ---- load tile: st -> LDS buf0 + regs; v, coeffs -> regs ----
    if (act) {
#pragma unroll
        for (int k = 0; k < 4; ++k) {
            int r = 4*rg + k;
            int h = (h0 + r - T) & 255;
            int g = (bz << 16) | (h << 8) | w;
            gidx[k] = g;
            float4 s = stI[g];
            st[k] = s;
            buf[0][r*TILE + col] = s;
            v[k]  = vI[g];
            k1[k] = c1[g];
            k2[k] = c2[g];
        }
    }
    __syncthreads();

    // clamped left/right LDS column offsets (garbage-in-garbage-region is fine)
    int cl = (col == 0)      ? 0  : col-1;
    int cr = (col == TILE-1) ? TILE-1 : col+1;

    // ---- T fused Jacobi iterations, one barrier each ----
    for (int s = 0; s < T; ++s) {
        const float4* __restrict__ cur = buf[s & 1];
        float4*       __restrict__ nxt = buf[(s & 1) ^ 1];
        if (act) {
            int r0 = 4*rg;
            float4 ns[4];
            // up/dn for interior of strip come from regs (old values kept in st[])
            float4 up0 = cur[((rg == 0) ? 0 : (r0-1))*TILE + col];
            float4 dn3 = cur[((rg == NRG-1) ? (TILE-1) : (r0+4))*TILE + col];
#pragma unroll
            for (int k = 0; k < 4; ++k) {
                int r = r0 + k;
                float4 lf = cur[r*TILE + cl];
                float4 rt = cur[r*TILE + cr];
                float4 up = (k == 0) ? up0 : st[k-1];
                float4 dn = (k == 3) ? dn3 : st[k+1];
                float4 S  = st[k];
                float4 K  = k1[k];
                float2 K2 = k2[k];
                float dmu = K.x*S.x + K.y + K.z*dn.x + K.w*rt.x
                          + K2.x*up.x + K2.y*lf.x;
                float dsg = K.x*S.y + K.z*S.z*dn.y + K.w*S.w*rt.y
                          + K2.x*up.z*up.y + K2.y*lf.w*lf.y;
                float dr0 = K.z*S.y*dn.y;
                float dr1 = K.w*S.y*rt.y;
                float4 V = v[k];
                V.x = 0.7f*V.x + 0.01f*dmu;
                V.y = 0.7f*V.y + 0.01f*dsg;
                V.z = 0.7f*V.z + 0.01f*dr0;
                V.w = 0.7f*V.w + 0.01f*dr1;
                v[k] = V;
                float4 o;
                o.x = clampf(S.x + V.x, 0.f, 63.f);
                o.y = clampf(S.y + V.y, 0.001f, 50.f);
                o.z = clampf(S.z + V.z, -0.99f, 0.99f);
                o.w = clampf(S.w + V.w, -0.99f, 0.99f);
                ns[k] = o;
            }
#pragma unroll
            for (int k = 0; k < 4; ++k) {
                st[k] = ns[k];
                nxt[(r0 + k)*TILE + col] = ns[k];
            }
        }
        __syncthreads();   // all reads of cur done AND nxt fully written
    }

    // ---- store interior (rows/cols [T, T+32)) ----
    if (act && col >= T && col < T+32) {
#pragma unroll
        for (int k = 0; k < 4; ++k) {
            int r = 4*rg + k;
            if (r >= T && r < T+32) {
                int g = gidx[k];
                if (mu_out) {
                    mu_out[g] = st[k].x;     // final launch: only mu needed
                } else {
                    stO[g] = st[k];
                    vO[g]  = v[k];
                }
            }
        }
    }
}

// ---- global max(edge_weight); gmax pre-zeroed via hipMemsetAsync ----
// (0u is the order-preserving encoding of the most-negative float)
__global__ void reduce_max_kernel(const float* __restrict__ ew, unsigned int* gmax) {
    int i = blockIdx.x*blockDim.x + threadIdx.x;
    float m = -INFINITY;
    for (; i < NEDGE; i += gridDim.x*blockDim.x) m = fmaxf(m, ew[i]);
#pragma unroll
    for (int off = 32; off > 0; off >>= 1)
        m = fmaxf(m, __shfl_down(m, off, 64));
    if ((threadIdx.x & 63) == 0) {
        unsigned u = __float_as_uint(m);
        unsigned key = (u & 0x80000000u) ? ~u : (u | 0x80000000u);
        atomicMax(gmax, key);
    }
}

// init state + momentum + invariant coefficient planes
__global__ __launch_bounds__(256) void init_state_kernel(
    const float*  __restrict__ y,
    const float2* __restrict__ ew,
    const float2* __restrict__ uw,
    const unsigned int* __restrict__ gmax_enc,
    float4* stA, float4* vA, float4* c1, float2* c2)
{
    int bh = blockIdx.x;
    int w  = threadIdx.x;
    int h  = bh & 255;
    int bbase = bh & ~255;
    int idx    = (bh << 8) | w;
    int idx_up = ((bbase | ((h-1)&255)) << 8) | w;
    int idx_lf = (bh << 8) | ((w-1)&255);

    unsigned key = *gmax_enc;
    unsigned u = (key & 0x80000000u) ? (key ^ 0x80000000u) : ~key;
    float gmax = __uint_as_float(u);
    float inv_denom = 1.f / (gmax*1.01f + 1.f);   // one-time, IEEE div fine

    float2 e   = ew[idx];
    float2 uwv = uw[idx];
    float  yv  = y[idx];
    float4 st;
    st.x = yv;
    st.y = 1.f;
    st.z = e.x * inv_denom;
    st.w = e.y * inv_denom;
    stA[idx] = st;
    vA[idx]  = make_float4(0.f, 0.f, 0.f, 0.f);
    c1[idx]  = make_float4(2.f*uwv.x, uwv.y*yv, e.x, e.y);
    c2[idx]  = make_float2(ew[idx_up].x, ew[idx_lf].y);
}

extern "C" void kernel_launch(void* const* d_in, const int* in_sizes, int n_in,
                              void* d_out, int out_size, void* d_ws, size_t ws_size,
                              hipStream_t stream) {
    const float* y  = (const float*)d_in[0];
    const float* ew = (const float*)d_in[1];
    const float* uw = (const float*)d_in[2];
    const int N = NPIX;

    // workspace: stA, stB, vA, vB, c1 (float4 planes) + c2 (float2) + 1 uint
    float4* stA = (float4*)d_ws;
    float4* stB = stA + N;
    float4* vA  = stB + N;
    float4* vB  = vA + N;
    float4* c1  = vB + N;
    float2* c2  = (float2*)(c1 + N);
    unsigned int* gmax = (unsigned int*)(c2 + N);

    hipMemsetAsync(gmax, 0, sizeof(unsigned int), stream);
    hipLaunchKernelGGL(reduce_max_kernel, dim3(512), dim3(256), 0, stream, ew, gmax);
    hipLaunchKernelGGL(init_state_kernel, dim3(N/256), dim3(256), 0, stream,
                       y, (const float2*)ew, (const float2*)uw, gmax,
                       stA, vA, c1, c2);

    float4 *stI = stA, *stO = stB, *vI = vA, *vO = vB;
    const int NLAUNCH = ITERS / T;   // 10
    for (int l = 0; l < NLAUNCH; ++l) {
        float* mo = (l == NLAUNCH-1) ? (float*)d_out : nullptr;
        hipLaunchKernelGGL(tile_kernel, dim3(8, 8, 4), dim3(1024), 0, stream,
                           stI, vI, stO, vO, c1, c2, mo);
        float4* t;
        t = stI; stI = stO; stO = t;
        t = vI;  vI  = vO;  vO  = t;
    }
}

// Round 7
// 257.348 us; speedup vs baseline: 4.6668x; 1.0025x over previous
//
#include <hip/hip_runtime.h>
#include <hip/hip_cooperative_groups.h>
#include <math.h>

namespace cg = cooperative_groups;

// B=4, H=256, W=256, 100 iters. Closed-form update (3-pt GH quadrature is
// exact for these degree<=4 integrands; log/NDC terms cancel):
//   dmu  = 2*uw1*mu + uw2*y + sum_edges ew*mu_nb
//   dsg  = 2*uw1*sg + sum_edges ew*rou_edge*sg_nb
//   drou = ew*sg_self*sg_nb        (per owned edge)
// Temporal blocking: T=10 iters/phase, 52x52 halo tile -> 32x32 interior.
// Round 7: persistent cooperative kernel — 10 phases in ONE launch with
// grid.sync between. Coefficients live in registers for the whole run;
// per phase only the halo ring st/v is re-read and the interior written
// (22 MB vs 57 MB per phase). Occupancy-query-gated with full fallback to
// the round-6 multi-launch path (which passed at 258 us).
#define NPIX  262144
#define NEDGE 524288
#define ITERS 100
#define T     10
#define NPH   10            // ITERS / T
#define TILE  52            // 32 + 2*T
#define NRG   13            // rowgroups of 4 rows: 13*4 = 52 exact
#define ACTIVE (TILE*NRG)   // 676 active threads of 1024

__device__ __forceinline__ float clampf(float x, float lo, float hi) {
    return fminf(fmaxf(x, lo), hi);
}

// ====================== persistent cooperative kernel ======================
// State float4 {mu, sigma, rou0(down-edge), rou1(right-edge)}.
// k1 = {2*uw1, uw2*y, ew0, ew1}; k2 = {ew0 of up-nb, ew1 of left-nb}.
__global__ __launch_bounds__(1024) void osi_coop(
    const float*  __restrict__ y,
    const float2* __restrict__ ew,
    const float2* __restrict__ uw,
    unsigned int* __restrict__ gmax_enc,   // pre-zeroed by hipMemsetAsync
    float4* __restrict__ stP,
    float4* __restrict__ vP,
    float* __restrict__ out)
{
    __shared__ float4 buf[TILE*TILE];      // 43.3 KB, single-buffered
    cg::grid_group grid = cg::this_grid();

    int tid = threadIdx.x;
    int rg  = tid / TILE;
    int col = tid - rg*TILE;
    bool act = (tid < ACTIVE);
    int bz = blockIdx.z;
    int h0 = blockIdx.y * 32;
    int w0 = blockIdx.x * 32;
    int w  = (w0 + col - T) & 255;
    bool cin = (col >= T) && (col < T+32);

    float4 st[4], v[4], k1[4], ns[4];
    float2 k2[4];
    int gidx[4];
    float yv[4];
    float m = -INFINITY;

    // ---- one-time load of invariants -> registers ----
    if (act) {
#pragma unroll
        for (int k = 0; k < 4; ++k) {
            int r = 4*rg + k;
            int h = (h0 + r - T) & 255;
            int g = (bz << 16) | (h << 8) | w;
            gidx[k] = g;
            float2 e = ew[g];
            float2 u = uw[g];
            yv[k] = y[g];
            k1[k] = make_float4(2.f*u.x, u.y*yv[k], e.x, e.y);
            int gup = (bz << 16) | (((h-1) & 255) << 8) | w;
            int glf = (bz << 16) | (h << 8) | ((w-1) & 255);
            k2[k] = make_float2(ew[gup].x, ew[glf].y);
            m = fmaxf(m, fmaxf(e.x, e.y));
        }
    }
    // global max(ew): wave reduce (all 64 lanes participate; inactive = -inf)
#pragma unroll
    for (int off = 32; off > 0; off >>= 1)
        m = fmaxf(m, __shfl_down(m, off, 64));
    if ((tid & 63) == 0) {
        unsigned u = __float_as_uint(m);
        unsigned key = (u & 0x80000000u) ? ~u : (u | 0x80000000u);
        atomicMax(gmax_enc, key);
    }
    __threadfence();
    grid.sync();
    __threadfence();

    // ---- init state in registers ----
    {
        unsigned key = __hip_atomic_load(gmax_enc, __ATOMIC_RELAXED,
                                         __HIP_MEMORY_SCOPE_AGENT);
        unsigned u = (key & 0x80000000u) ? (key ^ 0x80000000u) : ~key;
        float gmax = __uint_as_float(u);
        float inv_denom = 1.f / (gmax*1.01f + 1.f);   // one-time, IEEE div
#pragma unroll
        for (int k = 0; k < 4; ++k) {
            st[k] = make_float4(yv[k], 1.f, k1[k].z*inv_denom, k1[k].w*inv_denom);
            v[k]  = make_float4(0.f, 0.f, 0.f, 0.f);
        }
    }

    int cl = (col == 0)      ? 0      : col-1;   // clamped: garbage region ok
    int cr = (col == TILE-1) ? TILE-1 : col+1;

    // ---- 10 phases of T=10 fused Jacobi iterations ----
#pragma unroll 1
    for (int p = 0; p < NPH; ++p) {
        // populate LDS tile from registers
        if (act) {
#pragma unroll
            for (int k = 0; k < 4; ++k)
                buf[(4*rg + k)*TILE + col] = st[k];
        }
        __syncthreads();

#pragma unroll 1
        for (int s = 0; s < T; ++s) {
            if (act) {
                int r0 = 4*rg;
                float4 up0 = buf[((rg == 0)     ? 0        : (r0-1))*TILE + col];
                float4 dn3 = buf[((rg == NRG-1) ? (TILE-1) : (r0+4))*TILE + col];
#pragma unroll
                for (int k = 0; k < 4; ++k) {
                    int r = r0 + k;
                    float4 lf = buf[r*TILE + cl];
                    float4 rt = buf[r*TILE + cr];
                    float4 up = (k == 0) ? up0 : st[k-1];
                    float4 dn = (k == 3) ? dn3 : st[k+1];
                    float4 S  = st[k];
                    float4 K  = k1[k];
                    float2 K2 = k2[k];
                    float dmu = K.x*S.x + K.y + K.z*dn.x + K.w*rt.x
                              + K2.x*up.x + K2.y*lf.x;
                    float dsg = K.x*S.y + K.z*S.z*dn.y + K.w*S.w*rt.y
                              + K2.x*up.z*up.y + K2.y*lf.w*lf.y;
                    float dr0 = K.z*S.y*dn.y;
                    float dr1 = K.w*S.y*rt.y;
                    float4 V = v[k];
                    V.x = 0.7f*V.x + 0.01f*dmu;
                    V.y = 0.7f*V.y + 0.01f*dsg;
                    V.z = 0.7f*V.z + 0.01f*dr0;
                    V.w = 0.7f*V.w + 0.01f*dr1;
                    v[k] = V;
                    float4 o;
                    o.x = clampf(S.x + V.x, 0.f, 63.f);
                    o.y = clampf(S.y + V.y, 0.001f, 50.f);
                    o.z = clampf(S.z + V.z, -0.99f, 0.99f);
                    o.w = clampf(S.w + V.w, -0.99f, 0.99f);
                    ns[k] = o;
                }
            }
            __syncthreads();   // all reads of state-s done
            if (act) {
#pragma unroll
                for (int k = 0; k < 4; ++k) {
                    st[k] = ns[k];
                    buf[(4*rg + k)*TILE + col] = ns[k];
                }
            }
            __syncthreads();   // state-(s+1) visible
        }

        if (p < NPH-1) {
            // publish interior, sync grid, refresh halo from neighbors
            if (act) {
#pragma unroll
                for (int k = 0; k < 4; ++k) {
                    int r = 4*rg + k;
                    if (cin && r >= T && r < T+32) {
                        stP[gidx[k]] = st[k];
                        vP[gidx[k]]  = v[k];
                    }
                }
            }
            __threadfence();
            grid.sync();
            __threadfence();
            if (act) {
#pragma unroll
                for (int k = 0; k < 4; ++k) {
                    int r = 4*rg + k;
                    bool halo = !(cin && r >= T && r < T+32);
                    if (halo) {
                        st[k] = stP[gidx[k]];
                        v[k]  = vP[gidx[k]];
                    }
                }
            }
        } else {
            // final phase: interior mu -> output
            if (act) {
#pragma unroll
                for (int k = 0; k < 4; ++k) {
                    int r = 4*rg + k;
                    if (cin && r >= T && r < T+32)
                        out[gidx[k]] = st[k].x;
                }
            }
        }
    }
}

// ====================== round-6 fallback path ======================
__global__ __launch_bounds__(1024, 4) void tile_kernel(
    const float4* __restrict__ stI, const float4* __restrict__ vI,
    float4* __restrict__ stO, float4* __restrict__ vO,
    const float4* __restrict__ c1,
    const float2* __restrict__ c2,
    float* __restrict__ mu_out)
{
    __shared__ float4 buf[2][TILE*TILE];

    int tid = threadIdx.x;
    int rg  = tid / TILE;
    int col = tid - rg*TILE;
    bool act = (tid < ACTIVE);
    int bz = blockIdx.z;
    int h0 = blockIdx.y * 32;
    int w0 = blockIdx.x * 32;
    int w  = (w0 + col - T) & 255;

    float4 st[4], v[4], k1[4];
    float2 k2[4];
    int gidx[4];

    if (act) {
#pragma unroll
        for (int k = 0; k < 4; ++k) {
            int r = 4*rg + k;
            int h = (h0 + r - T) & 255;
            int g = (bz << 16) | (h << 8) | w;
            gidx[k] = g;
            float4 s = stI[g];
            st[k] = s;
            buf[0][r*TILE + col] = s;
            v[k]  = vI[g];
            k1[k] = c1[g];
            k2[k] = c2[g];
        }
    }
    __syncthreads();

    int cl = (col == 0)      ? 0  : col-1;
    int cr = (col == TILE-1) ? TILE-1 : col+1;

    for (int s = 0; s < T; ++s) {
        const float4* __restrict__ cur = buf[s & 1];
        float4*       __restrict__ nxt = buf[(s & 1) ^ 1];
        if (act) {
            int r0 = 4*rg;
            float4 ns[4];
            float4 up0 = cur[((rg == 0) ? 0 : (r0-1))*TILE + col];
            float4 dn3 = cur[((rg == NRG-1) ? (TILE-1) : (r0+4))*TILE + col];
#pragma unroll
            for (int k = 0; k < 4; ++k) {
                int r = r0 + k;
                float4 lf = cur[r*TILE + cl];
                float4 rt = cur[r*TILE + cr];
                float4 up = (k == 0) ? up0 : st[k-1];
                float4 dn = (k == 3) ? dn3 : st[k+1];
                float4 S  = st[k];
                float4 K  = k1[k];
                float2 K2 = k2[k];
                float dmu = K.x*S.x + K.y + K.z*dn.x + K.w*rt.x
                          + K2.x*up.x + K2.y*lf.x;
                float dsg = K.x*S.y + K.z*S.z*dn.y + K.w*S.w*rt.y
                          + K2.x*up.z*up.y + K2.y*lf.w*lf.y;
                float dr0 = K.z*S.y*dn.y;
                float dr1 = K.w*S.y*rt.y;
                float4 V = v[k];
                V.x = 0.7f*V.x + 0.01f*dmu;
                V.y = 0.7f*V.y + 0.01f*dsg;
                V.z = 0.7f*V.z + 0.01f*dr0;
                V.w = 0.7f*V.w + 0.01f*dr1;
                v[k] = V;
                float4 o;
                o.x = clampf(S.x + V.x, 0.f, 63.f);
                o.y = clampf(S.y + V.y, 0.001f, 50.f);
                o.z = clampf(S.z + V.z, -0.99f, 0.99f);
                o.w = clampf(S.w + V.w, -0.99f, 0.99f);
                ns[k] = o;
            }
#pragma unroll
            for (int k = 0; k < 4; ++k) {
                st[k] = ns[k];
                nxt[(r0 + k)*TILE + col] = ns[k];
            }
        }
        __syncthreads();
    }

    if (act && col >= T && col < T+32) {
#pragma unroll
        for (int k = 0; k < 4; ++k) {
            int r = 4*rg + k;
            if (r >= T && r < T+32) {
                int g = gidx[k];
                if (mu_out) {
                    mu_out[g] = st[k].x;
                } else {
                    stO[g] = st[k];
                    vO[g]  = v[k];
                }
            }
        }
    }
}

__global__ void reduce_max_kernel(const float* __restrict__ ew, unsigned int* gmax) {
    int i = blockIdx.x*blockDim.x + threadIdx.x;
    float m = -INFINITY;
    for (; i < NEDGE; i += gridDim.x*blockDim.x) m = fmaxf(m, ew[i]);
#pragma unroll
    for (int off = 32; off > 0; off >>= 1)
        m = fmaxf(m, __shfl_down(m, off, 64));
    if ((threadIdx.x & 63) == 0) {
        unsigned u = __float_as_uint(m);
        unsigned key = (u & 0x80000000u) ? ~u : (u | 0x80000000u);
        atomicMax(gmax, key);
    }
}

__global__ __launch_bounds__(256) void init_state_kernel(
    const float*  __restrict__ y,
    const float2* __restrict__ ew,
    const float2* __restrict__ uw,
    const unsigned int* __restrict__ gmax_enc,
    float4* stA, float4* vA, float4* c1, float2* c2)
{
    int bh = blockIdx.x;
    int w  = threadIdx.x;
    int h  = bh & 255;
    int bbase = bh & ~255;
    int idx    = (bh << 8) | w;
    int idx_up = ((bbase | ((h-1)&255)) << 8) | w;
    int idx_lf = (bh << 8) | ((w-1)&255);

    unsigned key = *gmax_enc;
    unsigned u = (key & 0x80000000u) ? (key ^ 0x80000000u) : ~key;
    float gmax = __uint_as_float(u);
    float inv_denom = 1.f / (gmax*1.01f + 1.f);

    float2 e   = ew[idx];
    float2 uwv = uw[idx];
    float  yv  = y[idx];
    float4 st;
    st.x = yv;
    st.y = 1.f;
    st.z = e.x * inv_denom;
    st.w = e.y * inv_denom;
    stA[idx] = st;
    vA[idx]  = make_float4(0.f, 0.f, 0.f, 0.f);
    c1[idx]  = make_float4(2.f*uwv.x, uwv.y*yv, e.x, e.y);
    c2[idx]  = make_float2(ew[idx_up].x, ew[idx_lf].y);
}

extern "C" void kernel_launch(void* const* d_in, const int* in_sizes, int n_in,
                              void* d_out, int out_size, void* d_ws, size_t ws_size,
                              hipStream_t stream) {
    const float* y  = (const float*)d_in[0];
    const float* ew = (const float*)d_in[1];
    const float* uw = (const float*)d_in[2];
    float* out = (float*)d_out;
    const int N = NPIX;

    // workspace: stA, stB, vA, vB, c1 (float4) + c2 (float2) + 1 uint
    float4* stA = (float4*)d_ws;
    float4* stB = stA + N;
    float4* vA  = stB + N;
    float4* vB  = vA + N;
    float4* c1  = vB + N;
    float2* c2  = (float2*)(c1 + N);
    unsigned int* gmax = (unsigned int*)(c2 + N);

    hipMemsetAsync(gmax, 0, sizeof(unsigned int), stream);

    // ---- try the persistent cooperative path (query-gated, deterministic) ----
    int dev = 0;
    hipGetDevice(&dev);
    int nCU = 0;
    hipDeviceGetAttribute(&nCU, hipDeviceAttributeMultiprocessorCount, dev);
    int maxB = 0;
    hipError_t qe = hipOccupancyMaxActiveBlocksPerMultiprocessor(
        &maxB, (const void*)osi_coop, 1024, 0);
    if (qe == hipSuccess && (long)maxB * nCU >= 256) {
        const float2* ew2 = (const float2*)ew;
        const float2* uw2 = (const float2*)uw;
        void* args[] = { (void*)&y, (void*)&ew2, (void*)&uw2, (void*)&gmax,
                         (void*)&stA, (void*)&vA, (void*)&out };
        hipError_t le = hipLaunchCooperativeKernel(
            (const void*)osi_coop, dim3(8, 8, 4), dim3(1024), args, 0, stream);
        if (le == hipSuccess) return;
    }

    // ---- fallback: round-6 multi-launch path (known-good, 258 us) ----
    hipLaunchKernelGGL(reduce_max_kernel, dim3(512), dim3(256), 0, stream, ew, gmax);
    hipLaunchKernelGGL(init_state_kernel, dim3(N/256), dim3(256), 0, stream,
                       y, (const float2*)ew, (const float2*)uw, gmax,
                       stA, vA, c1, c2);

    float4 *stI = stA, *stO = stB, *vI = vA, *vO = vB;
    const int NLAUNCH = ITERS / T;   // 10
    for (int l = 0; l < NLAUNCH; ++l) {
        float* mo = (l == NLAUNCH-1) ? out : nullptr;
        hipLaunchKernelGGL(tile_kernel, dim3(8, 8, 4), dim3(1024), 0, stream,
                           stI, vI, stO, vO, c1, c2, mo);
        float4* t;
        t = stI; stI = stO; stO = t;
        t = vI;  vI  = vO;  vO  = t;
    }
}

// Round 8
// 252.612 us; speedup vs baseline: 4.7543x; 1.0187x over previous
//
#include <hip/hip_runtime.h>
#include <math.h>

// B=4, H=256, W=256, 100 iters. Closed-form update (3-pt GH quadrature is
// exact for these degree<=4 integrands; log/NDC terms cancel):
//   dmu  = 2*uw1*mu + uw2*y + sum_edges ew*mu_nb
//   dsg  = 2*uw1*sg + sum_edges ew*rou_edge*sg_nb
//   drou = ew*sg_self*sg_nb        (per owned edge)
// Temporal blocking: T=10 iters/launch, 52x52 halo tile -> 32x32 interior,
// 256 blocks (1/CU), double-buffered LDS, 1 barrier/iter.
// Round 8: (a) LDS row stride padded 52->53: with stride 52 the 4-row
// rowgroup offset is 832 words = 0 mod 32, so lanes 52-63 alias lanes 0-11's
// banks in every b128 phase (measured SQ_LDS_BANK_CONFLICT=1.7e7 on the r7
// coop kernel). Stride 53 -> offset 16 mod 32, phase-disjoint.
// (b) c2 plane eliminated: neighbor ew comes from c1 staged through the idle
// dbuf half once per launch (edge px get finite garbage; shrinking-validity
// makes those px garbage anyway). (c) launch 0 synthesizes v=0 (no zero-plane
// load/store). Cooperative path removed: hipLaunchCooperativeKernel is not
// graph-capturable in this harness (r7 evidence: timed == fallback).
#define NPIX  262144
#define NEDGE 524288
#define ITERS 100
#define T     10
#define TILE  52            // 32 + 2*T
#define TS    53            // padded LDS row stride (float4 units)
#define NRG   13            // rowgroups of 4 rows: 13*4 = 52 exact
#define ACTIVE (TILE*NRG)   // 676 active threads of 1024

__device__ __forceinline__ float clampf(float x, float lo, float hi) {
    return fminf(fmaxf(x, lo), hi);
}

// State float4 {mu, sigma, rou0(down-edge), rou1(right-edge)}.
// c1 = {2*uw1, uw2*y, ew0, ew1}.
__global__ __launch_bounds__(1024, 4) void tile_kernel(
    const float4* __restrict__ stI, const float4* __restrict__ vI,
    float4* __restrict__ stO, float4* __restrict__ vO,
    const float4* __restrict__ c1,
    float* __restrict__ mu_out,   // non-null on last launch (st/v not stored)
    int first)                    // launch 0: v := 0, vI not read
{
    __shared__ float4 buf[2][TILE*TS];   // 88.3 KB

    int tid = threadIdx.x;
    int rg  = tid / TILE;
    int col = tid - rg*TILE;
    bool act = (tid < ACTIVE);
    int bz = blockIdx.z;
    int h0 = blockIdx.y * 32;
    int w0 = blockIdx.x * 32;
    int w  = (w0 + col - T) & 255;

    float4 st[4], v[4], k1[4];
    float2 k2[4];
    int gidx[4];

    // ---- load tile: st -> LDS buf0 + regs; c1 -> regs; ew pair -> buf1 ----
    float2* ews = (float2*)&buf[1][0];   // staging view, overwritten by iter 0
    if (act) {
#pragma unroll
        for (int k = 0; k < 4; ++k) {
            int r = 4*rg + k;
            int h = (h0 + r - T) & 255;
            int g = (bz << 16) | (h << 8) | w;
            gidx[k] = g;
            float4 s = stI[g];
            st[k] = s;
            buf[0][r*TS + col] = s;
            float4 K = c1[g];
            k1[k] = K;
            ews[r*TS + col] = make_float2(K.z, K.w);   // {ew0, ew1}
            v[k] = first ? make_float4(0.f, 0.f, 0.f, 0.f) : vI[g];
        }
    }
    __syncthreads();

    // gather neighbor ew: k2 = {ew0 of up-nb, ew1 of left-nb} (clamped at tile
    // edge -> finite garbage; edge px are garbage-region by construction)
    int cl = (col == 0)      ? 0      : col-1;
    int cr = (col == TILE-1) ? TILE-1 : col+1;
    if (act) {
#pragma unroll
        for (int k = 0; k < 4; ++k) {
            int r  = 4*rg + k;
            int ru = (r == 0) ? 0 : r-1;
            k2[k] = make_float2(ews[ru*TS + col].x, ews[r*TS + cl].y);
        }
    }
    __syncthreads();   // k2 reads done before iter-0 writes buf1

    // ---- T fused Jacobi iterations, one barrier each ----
    for (int s = 0; s < T; ++s) {
        const float4* __restrict__ cur = buf[s & 1];
        float4*       __restrict__ nxt = buf[(s & 1) ^ 1];
        if (act) {
            int r0 = 4*rg;
            float4 ns[4];
            float4 up0 = cur[((rg == 0) ? 0 : (r0-1))*TS + col];
            float4 dn3 = cur[((rg == NRG-1) ? (TILE-1) : (r0+4))*TS + col];
#pragma unroll
            for (int k = 0; k < 4; ++k) {
                int r = r0 + k;
                float4 lf = cur[r*TS + cl];
                float4 rt = cur[r*TS + cr];
                float4 up = (k == 0) ? up0 : st[k-1];
                float4 dn = (k == 3) ? dn3 : st[k+1];
                float4 S  = st[k];
                float4 K  = k1[k];
                float2 K2 = k2[k];
                float dmu = K.x*S.x + K.y + K.z*dn.x + K.w*rt.x
                          + K2.x*up.x + K2.y*lf.x;
                float dsg = K.x*S.y + K.z*S.z*dn.y + K.w*S.w*rt.y
                          + K2.x*up.z*up.y + K2.y*lf.w*lf.y;
                float dr0 = K.z*S.y*dn.y;
                float dr1 = K.w*S.y*rt.y;
                float4 V = v[k];
                V.x = 0.7f*V.x + 0.01f*dmu;
                V.y = 0.7f*V.y + 0.01f*dsg;
                V.z = 0.7f*V.z + 0.01f*dr0;
                V.w = 0.7f*V.w + 0.01f*dr1;
                v[k] = V;
                float4 o;
                o.x = clampf(S.x + V.x, 0.f, 63.f);
                o.y = clampf(S.y + V.y, 0.001f, 50.f);
                o.z = clampf(S.z + V.z, -0.99f, 0.99f);
                o.w = clampf(S.w + V.w, -0.99f, 0.99f);
                ns[k] = o;
            }
#pragma unroll
            for (int k = 0; k < 4; ++k) {
                st[k] = ns[k];
                nxt[(r0 + k)*TS + col] = ns[k];
            }
        }
        __syncthreads();   // all reads of cur done AND nxt fully written
    }

    // ---- store interior (rows/cols [T, T+32)) ----
    if (act && col >= T && col < T+32) {
#pragma unroll
        for (int k = 0; k < 4; ++k) {
            int r = 4*rg + k;
            if (r >= T && r < T+32) {
                int g = gidx[k];
                if (mu_out) {
                    mu_out[g] = st[k].x;     // final launch: only mu needed
                } else {
                    stO[g] = st[k];
                    vO[g]  = v[k];
                }
            }
        }
    }
}

// ---- global max(edge_weight); gmax pre-zeroed via hipMemsetAsync ----
// (0u is the order-preserving encoding of the most-negative float)
__global__ void reduce_max_kernel(const float* __restrict__ ew, unsigned int* gmax) {
    int i = blockIdx.x*blockDim.x + threadIdx.x;
    float m = -INFINITY;
    for (; i < NEDGE; i += gridDim.x*blockDim.x) m = fmaxf(m, ew[i]);
#pragma unroll
    for (int off = 32; off > 0; off >>= 1)
        m = fmaxf(m, __shfl_down(m, off, 64));
    if ((threadIdx.x & 63) == 0) {
        unsigned u = __float_as_uint(m);
        unsigned key = (u & 0x80000000u) ? ~u : (u | 0x80000000u);
        atomicMax(gmax, key);
    }
}

// init state + invariant coefficient plane (no v plane, no c2 plane)
__global__ __launch_bounds__(256) void init_state_kernel(
    const float*  __restrict__ y,
    const float2* __restrict__ ew,
    const float2* __restrict__ uw,
    const unsigned int* __restrict__ gmax_enc,
    float4* stA, float4* c1)
{
    int idx = blockIdx.x*256 + threadIdx.x;

    unsigned key = *gmax_enc;
    unsigned u = (key & 0x80000000u) ? (key ^ 0x80000000u) : ~key;
    float gmax = __uint_as_float(u);
    float inv_denom = 1.f / (gmax*1.01f + 1.f);   // one-time, IEEE div fine

    float2 e   = ew[idx];
    float2 uwv = uw[idx];
    float  yv  = y[idx];
    float4 st;
    st.x = yv;
    st.y = 1.f;
    st.z = e.x * inv_denom;
    st.w = e.y * inv_denom;
    stA[idx] = st;
    c1[idx]  = make_float4(2.f*uwv.x, uwv.y*yv, e.x, e.y);
}

extern "C" void kernel_launch(void* const* d_in, const int* in_sizes, int n_in,
                              void* d_out, int out_size, void* d_ws, size_t ws_size,
                              hipStream_t stream) {
    const float* y  = (const float*)d_in[0];
    const float* ew = (const float*)d_in[1];
    const float* uw = (const float*)d_in[2];
    float* out = (float*)d_out;
    const int N = NPIX;

    // workspace: stA, stB, vA, vB, c1 (float4 planes) + 1 uint (~21 MB)
    float4* stA = (float4*)d_ws;
    float4* stB = stA + N;
    float4* vA  = stB + N;
    float4* vB  = vA + N;
    float4* c1  = vB + N;
    unsigned int* gmax = (unsigned int*)(c1 + N);

    hipMemsetAsync(gmax, 0, sizeof(unsigned int), stream);
    hipLaunchKernelGGL(reduce_max_kernel, dim3(512), dim3(256), 0, stream, ew, gmax);
    hipLaunchKernelGGL(init_state_kernel, dim3(N/256), dim3(256), 0, stream,
                       y, (const float2*)ew, (const float2*)uw, gmax,
                       stA, c1);

    float4 *stI = stA, *stO = stB, *vI = vA, *vO = vB;
    const int NLAUNCH = ITERS / T;   // 10
    for (int l = 0; l < NLAUNCH; ++l) {
        float* mo = (l == NLAUNCH-1) ? out : nullptr;
        hipLaunchKernelGGL(tile_kernel, dim3(8, 8, 4), dim3(1024), 0, stream,
                           stI, vI, stO, vO, c1, mo, (l == 0) ? 1 : 0);
        float4* t;
        t = stI; stI = stO; stO = t;
        t = vI;  vI  = vO;  vO  = t;
    }
}